// Round 7
// baseline (118.973 us; speedup 1.0000x reference)
//
#include <hip/hip_runtime.h>
#include <hip/hip_bf16.h>

#define B_  8
#define T_  1024
#define DI_ 256
#define C_  1024
#define O_  1024
#define KW  9
#define BT_ 8192
#define EPSF 1e-12f

typedef unsigned short u16;
typedef u16   ushort8 __attribute__((ext_vector_type(8)));
typedef u16   ushort4v __attribute__((ext_vector_type(4)));
typedef __bf16 bf16x8 __attribute__((ext_vector_type(8)));
typedef float  f32x4  __attribute__((ext_vector_type(4)));

#define GLOAD_LDS16(g, l) __builtin_amdgcn_global_load_lds( \
    (const __attribute__((address_space(1))) void*)(g),      \
    (__attribute__((address_space(3))) void*)(l), 16, 0, 0)

__device__ __forceinline__ float bf2f(u16 u) {
    union { unsigned int i; float f; } z; z.i = ((unsigned int)u) << 16; return z.f;
}
__device__ __forceinline__ u16 f2bf(float f) {
    union { float f; unsigned int i; } z; z.f = f;
    unsigned int i = z.i;
    i += 0x7FFFu + ((i >> 16) & 1u);   // RNE
    return (u16)(i >> 16);
}
__device__ __forceinline__ float mishf(float v) {
    float u = __expf(v);
    float w = 1.f + u;
    return v * (1.f - 2.f / (w * w + 1.f));
}

// ================= mega prep kernel =========================================
#define PB_XB 2048
#define PB_W1 2304
#define PB_W2 2560
#define PB_DN 2568
#define PB_PT 4616

__global__ __launch_bounds__(256)
void prep_k(const float* __restrict__ x,   u16* __restrict__ xb,
            const float* __restrict__ w1w, u16* __restrict__ w1b16,
            const float* __restrict__ w2w, u16* __restrict__ w2b16,
            const float* __restrict__ d_w, const float* __restrict__ d_g,
            float* __restrict__ dwf,
            const float* __restrict__ p_w, const float* __restrict__ p_g,
            float* __restrict__ part, u16* __restrict__ pwT)
{
    const int bid = blockIdx.x;
    const int tid = threadIdx.x;

    if (bid < PB_W2) {
        const float* in;
        u16* out;
        int i;
        if (bid < PB_XB)      { in = x;   out = xb;    i = bid * 256 + tid; }
        else if (bid < PB_W1) { in = w1w; out = w1b16; i = (bid - PB_XB) * 256 + tid; }
        else                  { in = w2w; out = w2b16; i = (bid - PB_W1) * 256 + tid; }
        float4 v = ((const float4*)in)[i];
        ushort4v o;
        o.x = f2bf(v.x); o.y = f2bf(v.y); o.z = f2bf(v.z); o.w = f2bf(v.w);
        ((ushort4v*)out)[i] = o;
    } else if (bid < PB_DN) {
        __shared__ float red[KW][256];
        __shared__ float nrm[KW];
        const int b = bid - PB_W2;
        float s[KW];
#pragma unroll
        for (int k = 0; k < KW; k++) s[k] = 0.f;
        for (int c = tid; c < C_; c += 256) {
#pragma unroll
            for (int k = 0; k < KW; k++) {
                float v = d_w[((size_t)b * C_ + c) * KW + k];
                s[k] += v * v;
            }
        }
#pragma unroll
        for (int k = 0; k < KW; k++) red[k][tid] = s[k];
        __syncthreads();
        if (tid < KW) {
            float t = 0.f;
            for (int i = 0; i < 256; i++) t += red[tid][i];
            nrm[tid] = fmaxf(sqrtf(t), EPSF);
        }
        __syncthreads();
        for (int c = tid; c < C_; c += 256) {
            float g = d_g[(size_t)b * C_ + c];
#pragma unroll
            for (int k = 0; k < KW; k++)
                dwf[((size_t)b * C_ + c) * KW + k] =
                    d_w[((size_t)b * C_ + c) * KW + k] / nrm[k] * g;
        }
    } else {
        __shared__ float ts[64][65];
        __shared__ float sq[4][64];
        const int idx = bid - PB_DN;
        const int b   = idx >> 8;
        const int rem = idx & 255;
        const int c0  = (rem >> 4) * 64, o0 = (rem & 15) * 64;
        const int col = tid & 63;
        const int rg  = tid >> 6;
        float ssq = 0.f;
        for (int r = rg; r < 64; r += 4) {
            float v = p_w[((size_t)b * C_ + c0 + r) * O_ + o0 + col];
            ssq += v * v;
            ts[r][col] = v * p_g[(size_t)b * C_ + c0 + r];
        }
        sq[rg][col] = ssq;
        __syncthreads();
        if (tid < 64)
            part[((size_t)b * 16 + (rem >> 4)) * O_ + o0 + tid] =
                sq[0][tid] + sq[1][tid] + sq[2][tid] + sq[3][tid];
        for (int r = rg; r < 64; r += 4)
            pwT[((size_t)b * O_ + o0 + r) * C_ + c0 + col] = f2bf(ts[col][r]);
    }
}

// ---------------- depthwise conv along t + transpose write -------------------
__global__ __launch_bounds__(256)
void dwconv_k(const u16* __restrict__ h, const float* __restrict__ dwf,
              const float* __restrict__ d_b, u16* __restrict__ y1gT)
{
    __shared__ u16 hs[64][74];
    const int b  = blockIdx.z;
    const int c0 = blockIdx.y * 64, t0 = blockIdx.x * 64;
    const int tid = threadIdx.x;
    for (int idx = tid; idx < 64 * 72; idx += 256) {
        int cc = idx / 72, tt = idx % 72;
        int t = t0 + tt - 4;
        u16 v = 0;
        if (t >= 0 && t < T_) v = h[(size_t)(c0 + cc) * BT_ + b * T_ + t];
        hs[cc][tt] = v;
    }
    __syncthreads();
    const int cc = tid & 63;
    const int c  = c0 + cc;
    float w[KW];
#pragma unroll
    for (int k = 0; k < KW; k++) w[k] = dwf[((size_t)b * C_ + c) * KW + k];
    const float bb = d_b[(size_t)b * C_ + c];
    for (int tt = tid >> 6; tt < 64; tt += 4) {
        float s = bb;
#pragma unroll
        for (int k = 0; k < KW; k++) s += bf2f(hs[cc][tt + k]) * w[k];
        y1gT[((size_t)b * T_ + t0 + tt) * C_ + c] = f2bf(s);
    }
}

// ============ wide GEMM: BM=128, BN=256, BK=32, 4 waves of 64x128 ===========
// Fat per-wave tiles: 12 KB LDS reads per 32 MFMA (384 B/MFMA) to dodge the
// LDS-BW ceiling of the 4x4 structure. Dbuf LDS 48KB, T3-recipe loop,
// XOR swizzle (slot^row&3), XCD-chunked block swizzle, gload_lds w16.
// EPI 0: D(bf16) = mish(v + bias[row])
// EPI 1: D(bf16) = v*inv(part,col) + bias[col]   (per-batch Bt/bias/extra)
template<int EPI>
__device__ __forceinline__ void gemmw_body(
    const u16* __restrict__ A, const u16* __restrict__ Bt,
    u16* __restrict__ Db, const float* __restrict__ bias,
    const float* __restrict__ extra, int M, int N, int Kd)
{
    __shared__ u16 As[2][128 * 32];
    __shared__ u16 Bs[2][256 * 32];

    const int gx = gridDim.x;
    const unsigned nwg = (unsigned)gx * gridDim.y;
    unsigned lin = blockIdx.y * gx + blockIdx.x;
    lin = (lin & 7u) * (nwg >> 3) + (lin >> 3);
    const int m0 = (int)(lin / gx) * 128;
    const int n0 = (int)(lin % gx) * 256;

    const int b = (EPI == 1) ? (m0 >> 10) : 0;
    if (EPI == 1) {
        Bt    += (size_t)b * O_ * C_;
        bias  += (size_t)b * O_;
        extra += (size_t)b * 16 * O_;
    }

    const int tid  = threadIdx.x;
    const int lane = tid & 63, wave = tid >> 6;
    const int wm = (wave >> 1) * 64, wn = (wave & 1) * 128;
    const int lr = lane & 15;

    // staging: one gload_lds = 16 rows x 64B; source col slot pre-swizzled
    const int srow  = lane >> 2;                       // 0..15
    const int scolE = ((lane & 3) ^ (srow & 3)) * 8;   // elems

    f32x4 acc[4][8];
#pragma unroll
    for (int i = 0; i < 4; i++)
#pragma unroll
        for (int j = 0; j < 8; j++) acc[i][j] = (f32x4){0.f, 0.f, 0.f, 0.f};

    auto STAGE = [&](int buf, int k0) {
#pragma unroll
        for (int i = 0; i < 2; i++)
            GLOAD_LDS16(&A[(size_t)(m0 + i * 64 + wave * 16 + srow) * Kd + k0 + scolE],
                        &As[buf][(i * 64 + wave * 16) * 32]);
#pragma unroll
        for (int i = 0; i < 4; i++)
            GLOAD_LDS16(&Bt[(size_t)(n0 + i * 64 + wave * 16 + srow) * Kd + k0 + scolE],
                        &Bs[buf][(i * 64 + wave * 16) * 32]);
    };

    const int NT = Kd >> 5;
    STAGE(0, 0);
    for (int kt = 0; kt < NT; kt++) {
        __syncthreads();                 // drains STAGE(kt) after prev MFMA phase
        if (kt + 1 < NT) STAGE((kt + 1) & 1, (kt + 1) << 5);
        const u16* as = As[kt & 1];
        const u16* bs = Bs[kt & 1];
        const int slot = lane >> 4;                   // 0..3
        const int sw = (slot ^ (lr & 3)) << 3;
        bf16x8 av[4], bv[8];
#pragma unroll
        for (int i = 0; i < 4; i++)
            av[i] = *(const bf16x8*)&as[(wm + i * 16 + lr) * 32 + sw];
#pragma unroll
        for (int j = 0; j < 8; j++)
            bv[j] = *(const bf16x8*)&bs[(wn + j * 16 + lr) * 32 + sw];
#pragma unroll
        for (int i = 0; i < 4; i++)
#pragma unroll
            for (int j = 0; j < 8; j++)
                acc[i][j] = __builtin_amdgcn_mfma_f32_16x16x32_bf16(
                    av[i], bv[j], acc[i][j], 0, 0, 0);
    }

    const int r0 = (lane >> 4) * 4;
#pragma unroll
    for (int i = 0; i < 4; i++) {
#pragma unroll
        for (int j = 0; j < 8; j++) {
            const int col = n0 + wn + j * 16 + lr;
            float iv = 0.f;
            if (EPI == 1) {
                float s = 0.f;
#pragma unroll
                for (int ch = 0; ch < 16; ch++)
                    s += extra[(size_t)ch * O_ + col];
                iv = 1.f / fmaxf(sqrtf(s), EPSF);
            }
#pragma unroll
            for (int r = 0; r < 4; r++) {
                const int row = m0 + wm + i * 16 + r0 + r;
                float v = acc[i][j][r];
                if (EPI == 0) {
                    v += bias[row];
                    v = mishf(v);
                } else {
                    v = v * iv + bias[col];
                }
                Db[(size_t)row * N + col] = f2bf(v);
            }
        }
    }
}

__global__ __launch_bounds__(256, 1)
void gemm1_k(const u16* __restrict__ A, const u16* __restrict__ Bt,
             u16* __restrict__ D, const float* __restrict__ bias,
             int M, int N, int Kd)
{
    gemmw_body<0>(A, Bt, D, bias, nullptr, M, N, Kd);
}

__global__ __launch_bounds__(256, 1)
void gemm2_k(const u16* __restrict__ A, const u16* __restrict__ Bt,
             u16* __restrict__ D, const float* __restrict__ bias,
             const float* __restrict__ extra, int M, int N, int Kd)
{
    gemmw_body<1>(A, Bt, D, bias, extra, M, N, Kd);
}

// ============ GEMM3: 128x64 tile, BK=64 dbuf (memory-bound epilogue GEMM) ===
__global__ __launch_bounds__(256)
void gemm3_k(const u16* __restrict__ A, const u16* __restrict__ Bt,
             float* __restrict__ Df, const float* __restrict__ bias,
             const float* __restrict__ X, int M, int N, int Kd)
{
    __shared__ u16 As[2][128 * 64];
    __shared__ u16 Bs[2][64 * 64];

    const int gx = gridDim.x;
    const unsigned nwg = (unsigned)gx * gridDim.y;
    unsigned lin = blockIdx.y * gx + blockIdx.x;
    lin = (lin & 7u) * (nwg >> 3) + (lin >> 3);
    const int m0 = (int)(lin / gx) * 128;
    const int n0 = (int)(lin % gx) * 64;

    const int tid  = threadIdx.x;
    const int lane = tid & 63, wave = tid >> 6;
    const int wm = (wave & 1) * 64, wn = (wave >> 1) * 32;
    const int lr = lane & 15;

    const int sbase = wave * 8;
    const int srowL = lane >> 3;
    const int scolE = ((lane & 7) ^ srowL) * 8;

    f32x4 acc[4][2];
#pragma unroll
    for (int i = 0; i < 4; i++)
#pragma unroll
        for (int j = 0; j < 2; j++) acc[i][j] = (f32x4){0.f, 0.f, 0.f, 0.f};

    auto STAGE = [&](int buf, int k0) {
#pragma unroll
        for (int i = 0; i < 4; i++)
            GLOAD_LDS16(&A[(size_t)(m0 + i * 32 + sbase + srowL) * Kd + k0 + scolE],
                        &As[buf][(i * 32 + sbase) * 64]);
#pragma unroll
        for (int i = 0; i < 2; i++)
            GLOAD_LDS16(&Bt[(size_t)(n0 + i * 32 + sbase + srowL) * Kd + k0 + scolE],
                        &Bs[buf][(i * 32 + sbase) * 64]);
    };

    const int NT = Kd >> 6;
    STAGE(0, 0);
    for (int kt = 0; kt < NT; kt++) {
        __syncthreads();
        if (kt + 1 < NT) STAGE((kt + 1) & 1, (kt + 1) << 6);
        const u16* as = As[kt & 1];
        const u16* bs = Bs[kt & 1];
        bf16x8 av[2][4], bv[2][2];
#pragma unroll
        for (int kk = 0; kk < 2; kk++) {
            const int slot = (lane >> 4) + kk * 4;
            const int sw = (slot ^ (lr & 7)) << 3;
#pragma unroll
            for (int i = 0; i < 4; i++)
                av[kk][i] = *(const bf16x8*)&as[(wm + i * 16 + lr) * 64 + sw];
#pragma unroll
            for (int j = 0; j < 2; j++)
                bv[kk][j] = *(const bf16x8*)&bs[(wn + j * 16 + lr) * 64 + sw];
        }
#pragma unroll
        for (int kk = 0; kk < 2; kk++)
#pragma unroll
            for (int i = 0; i < 4; i++)
#pragma unroll
                for (int j = 0; j < 2; j++)
                    acc[i][j] = __builtin_amdgcn_mfma_f32_16x16x32_bf16(
                        av[kk][i], bv[kk][j], acc[i][j], 0, 0, 0);
    }

    const int r0 = (lane >> 4) * 4;
#pragma unroll
    for (int i = 0; i < 4; i++) {
#pragma unroll
        for (int j = 0; j < 2; j++) {
            const int col = n0 + wn + j * 16 + lr;
#pragma unroll
            for (int r = 0; r < 4; r++) {
                const int row = m0 + wm + i * 16 + r0 + r;
                Df[(size_t)row * N + col] =
                    acc[i][j][r] + bias[col] + X[(size_t)row * N + col];
            }
        }
    }
}

extern "C" void kernel_launch(void* const* d_in, const int* in_sizes, int n_in,
                              void* d_out, int out_size, void* d_ws, size_t ws_size,
                              hipStream_t stream)
{
    const float* x   = (const float*)d_in[0];
    const float* d_w = (const float*)d_in[1];
    const float* d_g = (const float*)d_in[2];
    const float* d_b = (const float*)d_in[3];
    const float* p_w = (const float*)d_in[4];
    const float* p_g = (const float*)d_in[5];
    const float* p_b = (const float*)d_in[6];
    const float* w1w = (const float*)d_in[7];
    const float* w1b = (const float*)d_in[8];
    const float* w2w = (const float*)d_in[9];
    const float* w2b = (const float*)d_in[10];
    float* out = (float*)d_out;

    char* ws = (char*)d_ws;
    const size_t SZ = (size_t)16777216;           // 16 MB
    u16*   h    = (u16*)(ws);                     // [C][B*T] bf16
    u16*   y1gT = (u16*)(ws + SZ);                // [B*T][C] bf16
    u16*   pwT  = (u16*)(ws + 2 * SZ);            // [B][O][C] bf16
    u16*   y2T  = (u16*)(ws + 3 * SZ);            // [B*T][O] bf16
    u16*   xb   = (u16*)(ws + 4 * SZ);            // [B*T][DI] bf16 (4 MB)
    u16*   w1b16= (u16*)(ws + 4 * SZ + 4194304);  // [C][DI] bf16
    u16*   w2b16= (u16*)(ws + 4 * SZ + 4718592);  // [DI][O] bf16
    float* dwf  = (float*)(ws + 4 * SZ + 5242880);           // B*C*KW f32
    float* part = (float*)(ws + 4 * SZ + 5242880 + 294912);  // B*16*O f32

    prep_k<<<dim3(PB_PT), 256, 0, stream>>>(
        x, xb, w1w, w1b16, w2w, w2b16, d_w, d_g, dwf, p_w, p_g, part, pwT);

    // GEMM1: h[c][bt] = mish(w1[c,:] . xb[bt,:] + w1b[c]);  M=C, N=B*T, K=DI
    gemm1_k<<<dim3(BT_ / 256, C_ / 128), 256, 0, stream>>>(
        w1b16, xb, h, w1b, C_, BT_, DI_);

    dwconv_k<<<dim3(T_ / 64, C_ / 64, B_), 256, 0, stream>>>(h, dwf, d_b, y1gT);

    // GEMM2: y2T[bt][o] = (y1gT[bt,:] . pwT[b][o,:])*inv[b][o] + p_b[b][o]
    gemm2_k<<<dim3(O_ / 256, BT_ / 128), 256, 0, stream>>>(
        y1gT, pwT, y2T, p_b, part, BT_, O_, C_);

    // GEMM3: out[bt][i] = y2T[bt,:] . w2[i,:] + w2b[i] + x[bt][i];  N=DI
    gemm3_k<<<dim3(DI_ / 64, BT_ / 128), 256, 0, stream>>>(
        y2T, w2b16, out, w2b, x, BT_, DI_, O_);
}

// Round 8
// 106.252 us; speedup vs baseline: 1.1197x; 1.1197x over previous
//
#include <hip/hip_runtime.h>
#include <hip/hip_bf16.h>

#define B_  8
#define T_  1024
#define DI_ 256
#define C_  1024
#define O_  1024
#define KW  9
#define BT_ 8192
#define EPSF 1e-12f

typedef unsigned short u16;
typedef u16   ushort8 __attribute__((ext_vector_type(8)));
typedef u16   ushort4v __attribute__((ext_vector_type(4)));
typedef __bf16 bf16x8 __attribute__((ext_vector_type(8)));
typedef float  f32x4  __attribute__((ext_vector_type(4)));

#define GLOAD_LDS16(g, l) __builtin_amdgcn_global_load_lds( \
    (const __attribute__((address_space(1))) void*)(g),      \
    (__attribute__((address_space(3))) void*)(l), 16, 0, 0)

__device__ __forceinline__ float bf2f(u16 u) {
    union { unsigned int i; float f; } z; z.i = ((unsigned int)u) << 16; return z.f;
}
__device__ __forceinline__ u16 f2bf(float f) {
    union { float f; unsigned int i; } z; z.f = f;
    unsigned int i = z.i;
    i += 0x7FFFu + ((i >> 16) & 1u);   // RNE
    return (u16)(i >> 16);
}
__device__ __forceinline__ float mishf(float v) {
    float u = __expf(v);
    float w = 1.f + u;
    return v * (1.f - 2.f / (w * w + 1.f));
}

// ================= mega prep kernel =========================================
#define PB_XB 2048
#define PB_W1 2304
#define PB_W2 2560
#define PB_DN 2568
#define PB_PT 4616

__global__ __launch_bounds__(256)
void prep_k(const float* __restrict__ x,   u16* __restrict__ xb,
            const float* __restrict__ w1w, u16* __restrict__ w1b16,
            const float* __restrict__ w2w, u16* __restrict__ w2b16,
            const float* __restrict__ d_w, const float* __restrict__ d_g,
            float* __restrict__ dwf,
            const float* __restrict__ p_w, const float* __restrict__ p_g,
            float* __restrict__ part, u16* __restrict__ pwT)
{
    const int bid = blockIdx.x;
    const int tid = threadIdx.x;

    if (bid < PB_W2) {
        const float* in;
        u16* out;
        int i;
        if (bid < PB_XB)      { in = x;   out = xb;    i = bid * 256 + tid; }
        else if (bid < PB_W1) { in = w1w; out = w1b16; i = (bid - PB_XB) * 256 + tid; }
        else                  { in = w2w; out = w2b16; i = (bid - PB_W1) * 256 + tid; }
        float4 v = ((const float4*)in)[i];
        ushort4v o;
        o.x = f2bf(v.x); o.y = f2bf(v.y); o.z = f2bf(v.z); o.w = f2bf(v.w);
        ((ushort4v*)out)[i] = o;
    } else if (bid < PB_DN) {
        __shared__ float red[KW][256];
        __shared__ float nrm[KW];
        const int b = bid - PB_W2;
        float s[KW];
#pragma unroll
        for (int k = 0; k < KW; k++) s[k] = 0.f;
        for (int c = tid; c < C_; c += 256) {
#pragma unroll
            for (int k = 0; k < KW; k++) {
                float v = d_w[((size_t)b * C_ + c) * KW + k];
                s[k] += v * v;
            }
        }
#pragma unroll
        for (int k = 0; k < KW; k++) red[k][tid] = s[k];
        __syncthreads();
        if (tid < KW) {
            float t = 0.f;
            for (int i = 0; i < 256; i++) t += red[tid][i];
            nrm[tid] = fmaxf(sqrtf(t), EPSF);
        }
        __syncthreads();
        for (int c = tid; c < C_; c += 256) {
            float g = d_g[(size_t)b * C_ + c];
#pragma unroll
            for (int k = 0; k < KW; k++)
                dwf[((size_t)b * C_ + c) * KW + k] =
                    d_w[((size_t)b * C_ + c) * KW + k] / nrm[k] * g;
        }
    } else {
        __shared__ float ts[64][65];
        __shared__ float sq[4][64];
        const int idx = bid - PB_DN;
        const int b   = idx >> 8;
        const int rem = idx & 255;
        const int c0  = (rem >> 4) * 64, o0 = (rem & 15) * 64;
        const int col = tid & 63;
        const int rg  = tid >> 6;
        float ssq = 0.f;
        for (int r = rg; r < 64; r += 4) {
            float v = p_w[((size_t)b * C_ + c0 + r) * O_ + o0 + col];
            ssq += v * v;
            ts[r][col] = v * p_g[(size_t)b * C_ + c0 + r];
        }
        sq[rg][col] = ssq;
        __syncthreads();
        if (tid < 64)
            part[((size_t)b * 16 + (rem >> 4)) * O_ + o0 + tid] =
                sq[0][tid] + sq[1][tid] + sq[2][tid] + sq[3][tid];
        for (int r = rg; r < 64; r += 4)
            pwT[((size_t)b * O_ + o0 + r) * C_ + c0 + col] = f2bf(ts[col][r]);
    }
}

// ---------------- depthwise conv along t + transpose write -------------------
__global__ __launch_bounds__(256)
void dwconv_k(const u16* __restrict__ h, const float* __restrict__ dwf,
              const float* __restrict__ d_b, u16* __restrict__ y1gT)
{
    __shared__ u16 hs[64][74];
    const int b  = blockIdx.z;
    const int c0 = blockIdx.y * 64, t0 = blockIdx.x * 64;
    const int tid = threadIdx.x;
    for (int idx = tid; idx < 64 * 72; idx += 256) {
        int cc = idx / 72, tt = idx % 72;
        int t = t0 + tt - 4;
        u16 v = 0;
        if (t >= 0 && t < T_) v = h[(size_t)(c0 + cc) * BT_ + b * T_ + t];
        hs[cc][tt] = v;
    }
    __syncthreads();
    const int cc = tid & 63;
    const int c  = c0 + cc;
    float w[KW];
#pragma unroll
    for (int k = 0; k < KW; k++) w[k] = dwf[((size_t)b * C_ + c) * KW + k];
    const float bb = d_b[(size_t)b * C_ + c];
    for (int tt = tid >> 6; tt < 64; tt += 4) {
        float s = bb;
#pragma unroll
        for (int k = 0; k < KW; k++) s += bf2f(hs[cc][tt + k]) * w[k];
        y1gT[((size_t)b * T_ + t0 + tt) * C_ + c] = f2bf(s);
    }
}

// ===== GEMM: 128 x (TNF*32) tile, BK=32, 3-buf LDS, counted-vmcnt pipeline ==
// T4: per K-step wait vmcnt(only stage kt), stage kt+1 stays in flight across
// the raw s_barrier -> ~2 steps of latency cover. 3 blocks/CU co-resident.
// Both-sides XOR swizzle: LDS slot t of row r holds global 16B-slot t^(r&3).
// EPI 0: D(bf16) = mish(v + bias[row])
// EPI 1: D(bf16) = v*inv(part,col) + bias[col]   (per-batch Bt/bias/extra)
// EPI 2: D(f32)  = v + bias[col] + X[row,col]
template<int EPI, int TNF>
__device__ __forceinline__ void gemm_body(
    const u16* __restrict__ A, const u16* __restrict__ Bt,
    void* __restrict__ Dv, const float* __restrict__ bias,
    const float* __restrict__ extra, int M, int N, int Kd)
{
    __shared__ u16 As[3 * 4096];
    __shared__ u16 Bs[3 * 1024 * TNF];

    const int gx = gridDim.x;
    const unsigned nwg = (unsigned)gx * gridDim.y;
    unsigned lin = blockIdx.y * gx + blockIdx.x;
    lin = (lin & 7u) * (nwg >> 3) + (lin >> 3);
    const int m0 = (int)(lin / gx) * 128;
    const int n0 = (int)(lin % gx) * (TNF * 32);

    const int b = (EPI == 1) ? (m0 >> 10) : 0;
    if (EPI == 1) {
        Bt    += (size_t)b * O_ * C_;
        bias  += (size_t)b * O_;
        extra += (size_t)b * 16 * O_;
    }
    u16*   Db = (EPI == 2) ? nullptr : (u16*)Dv;
    float* Df = (EPI == 2) ? (float*)Dv : nullptr;
    const float* X = (EPI == 2) ? extra : nullptr;

    const int tid  = threadIdx.x;
    const int lane = tid & 63, wave = tid >> 6;
    const int wm = (wave & 1) * 64, wn = (wave >> 1) * (TNF * 16);
    const int lr = lane & 15;
    const int q  = lane >> 4;                         // 16B col slot 0..3
    const int srow  = lane >> 2;                      // 0..15 in 16-row chunk
    const int scolE = ((lane & 3) ^ (srow & 3)) * 8;  // pre-swizzled src col
    const int sw    = (q ^ (lr & 3)) << 3;            // swizzled read offset

    f32x4 acc[4][TNF];
#pragma unroll
    for (int i = 0; i < 4; i++)
#pragma unroll
        for (int j = 0; j < TNF; j++) acc[i][j] = (f32x4){0.f, 0.f, 0.f, 0.f};

    auto STAGE = [&](int buf, int kt) {
        const int k0 = kt << 5;
#pragma unroll
        for (int i = 0; i < 2; i++)
            GLOAD_LDS16(&A[(size_t)(m0 + i * 64 + wave * 16 + srow) * Kd + k0 + scolE],
                        &As[buf * 4096 + (i * 64 + wave * 16) * 32]);
#pragma unroll
        for (int i = 0; i < TNF / 2; i++)
            GLOAD_LDS16(&Bt[(size_t)(n0 + i * 64 + wave * 16 + srow) * Kd + k0 + scolE],
                        &Bs[buf * (1024 * TNF) + (i * 64 + wave * 16) * 32]);
    };

    const int NT = Kd >> 5;
    STAGE(0, 0);
    STAGE(1, 1);
    int rb = 0, sb = 2;
    for (int kt = 0; kt < NT; kt++) {
        if (kt == NT - 1) {
            asm volatile("s_waitcnt vmcnt(0)" ::: "memory");
        } else if constexpr (TNF == 4) {
            asm volatile("s_waitcnt vmcnt(4)" ::: "memory");
        } else {
            asm volatile("s_waitcnt vmcnt(3)" ::: "memory");
        }
        __builtin_amdgcn_s_barrier();
        if (kt + 2 < NT) STAGE(sb, kt + 2);
        const u16* as = &As[rb * 4096];
        const u16* bs = &Bs[rb * (1024 * TNF)];
        bf16x8 av[4], bv[TNF];
#pragma unroll
        for (int i = 0; i < 4; i++)
            av[i] = *(const bf16x8*)&as[(wm + i * 16 + lr) * 32 + sw];
#pragma unroll
        for (int j = 0; j < TNF; j++)
            bv[j] = *(const bf16x8*)&bs[(wn + j * 16 + lr) * 32 + sw];
#pragma unroll
        for (int i = 0; i < 4; i++)
#pragma unroll
            for (int j = 0; j < TNF; j++)
                acc[i][j] = __builtin_amdgcn_mfma_f32_16x16x32_bf16(
                    av[i], bv[j], acc[i][j], 0, 0, 0);
        rb = (rb == 2) ? 0 : rb + 1;
        sb = (sb == 2) ? 0 : sb + 1;
    }

    const int r0 = (lane >> 4) * 4;
#pragma unroll
    for (int i = 0; i < 4; i++) {
#pragma unroll
        for (int j = 0; j < TNF; j++) {
            const int col = n0 + wn + j * 16 + lr;
            float iv = 0.f;
            if (EPI == 1) {
                float s = 0.f;
#pragma unroll
                for (int ch = 0; ch < 16; ch++)
                    s += extra[(size_t)ch * O_ + col];
                iv = 1.f / fmaxf(sqrtf(s), EPSF);
            }
#pragma unroll
            for (int r = 0; r < 4; r++) {
                const int row = m0 + wm + i * 16 + r0 + r;
                float v = acc[i][j][r];
                if (EPI == 0) {
                    v += bias[row];
                    v = mishf(v);
                    Db[(size_t)row * N + col] = f2bf(v);
                } else if (EPI == 1) {
                    v = v * iv + bias[col];
                    Db[(size_t)row * N + col] = f2bf(v);
                } else {
                    v += bias[col] + X[(size_t)row * N + col];
                    Df[(size_t)row * N + col] = v;
                }
            }
        }
    }
}

__global__ __launch_bounds__(256, 3)
void gemm1_k(const u16* __restrict__ A, const u16* __restrict__ Bt,
             u16* __restrict__ D, const float* __restrict__ bias,
             int M, int N, int Kd)
{
    gemm_body<0, 4>(A, Bt, D, bias, nullptr, M, N, Kd);
}

__global__ __launch_bounds__(256, 3)
void gemm2_k(const u16* __restrict__ A, const u16* __restrict__ Bt,
             u16* __restrict__ D, const float* __restrict__ bias,
             const float* __restrict__ extra, int M, int N, int Kd)
{
    gemm_body<1, 4>(A, Bt, D, bias, extra, M, N, Kd);
}

__global__ __launch_bounds__(256, 3)
void gemm3_k(const u16* __restrict__ A, const u16* __restrict__ Bt,
             float* __restrict__ D, const float* __restrict__ bias,
             const float* __restrict__ X, int M, int N, int Kd)
{
    gemm_body<2, 2>(A, Bt, (void*)D, bias, X, M, N, Kd);
}

extern "C" void kernel_launch(void* const* d_in, const int* in_sizes, int n_in,
                              void* d_out, int out_size, void* d_ws, size_t ws_size,
                              hipStream_t stream)
{
    const float* x   = (const float*)d_in[0];
    const float* d_w = (const float*)d_in[1];
    const float* d_g = (const float*)d_in[2];
    const float* d_b = (const float*)d_in[3];
    const float* p_w = (const float*)d_in[4];
    const float* p_g = (const float*)d_in[5];
    const float* p_b = (const float*)d_in[6];
    const float* w1w = (const float*)d_in[7];
    const float* w1b = (const float*)d_in[8];
    const float* w2w = (const float*)d_in[9];
    const float* w2b = (const float*)d_in[10];
    float* out = (float*)d_out;

    char* ws = (char*)d_ws;
    const size_t SZ = (size_t)16777216;           // 16 MB
    u16*   h    = (u16*)(ws);                     // [C][B*T] bf16
    u16*   y1gT = (u16*)(ws + SZ);                // [B*T][C] bf16
    u16*   pwT  = (u16*)(ws + 2 * SZ);            // [B][O][C] bf16
    u16*   y2T  = (u16*)(ws + 3 * SZ);            // [B*T][O] bf16
    u16*   xb   = (u16*)(ws + 4 * SZ);            // [B*T][DI] bf16 (4 MB)
    u16*   w1b16= (u16*)(ws + 4 * SZ + 4194304);  // [C][DI] bf16
    u16*   w2b16= (u16*)(ws + 4 * SZ + 4718592);  // [DI][O] bf16
    float* dwf  = (float*)(ws + 4 * SZ + 5242880);           // B*C*KW f32
    float* part = (float*)(ws + 4 * SZ + 5242880 + 294912);  // B*16*O f32

    prep_k<<<dim3(PB_PT), 256, 0, stream>>>(
        x, xb, w1w, w1b16, w2w, w2b16, d_w, d_g, dwf, p_w, p_g, part, pwT);

    // GEMM1: h[c][bt] = mish(w1[c,:] . xb[bt,:] + w1b[c]);  M=C, N=B*T, K=DI
    gemm1_k<<<dim3(BT_ / 128, C_ / 128), 256, 0, stream>>>(
        w1b16, xb, h, w1b, C_, BT_, DI_);

    dwconv_k<<<dim3(T_ / 64, C_ / 64, B_), 256, 0, stream>>>(h, dwf, d_b, y1gT);

    // GEMM2: y2T[bt][o] = (y1gT[bt,:] . pwT[b][o,:])*inv[b][o] + p_b[b][o]
    gemm2_k<<<dim3(O_ / 128, BT_ / 128), 256, 0, stream>>>(
        y1gT, pwT, y2T, p_b, part, BT_, O_, C_);

    // GEMM3: out[bt][i] = y2T[bt,:] . w2[i,:] + w2b[i] + x[bt][i];  N=DI
    gemm3_k<<<dim3(DI_ / 64, BT_ / 128), 256, 0, stream>>>(
        y2T, w2b16, out, w2b, x, BT_, DI_, O_);
}

// Round 9
// 106.009 us; speedup vs baseline: 1.1223x; 1.0023x over previous
//
#include <hip/hip_runtime.h>
#include <hip/hip_bf16.h>

#define B_  8
#define T_  1024
#define DI_ 256
#define C_  1024
#define O_  1024
#define KW  9
#define BT_ 8192
#define EPSF 1e-12f

typedef unsigned short u16;
typedef u16   ushort8 __attribute__((ext_vector_type(8)));
typedef u16   ushort4v __attribute__((ext_vector_type(4)));
typedef __bf16 bf16x8 __attribute__((ext_vector_type(8)));
typedef float  f32x4  __attribute__((ext_vector_type(4)));

#define GLOAD_LDS16(g, l) __builtin_amdgcn_global_load_lds( \
    (const __attribute__((address_space(1))) void*)(g),      \
    (__attribute__((address_space(3))) void*)(l), 16, 0, 0)

__device__ __forceinline__ float bf2f(u16 u) {
    union { unsigned int i; float f; } z; z.i = ((unsigned int)u) << 16; return z.f;
}
__device__ __forceinline__ u16 f2bf(float f) {
    union { float f; unsigned int i; } z; z.f = f;
    unsigned int i = z.i;
    i += 0x7FFFu + ((i >> 16) & 1u);   // RNE
    return (u16)(i >> 16);
}
__device__ __forceinline__ float mishf(float v) {
    float u = __expf(v);
    float w = 1.f + u;
    return v * (1.f - 2.f / (w * w + 1.f));
}

// ================= mega prep kernel =========================================
#define PB_XB 2048
#define PB_W1 2304
#define PB_W2 2560
#define PB_DN 2568
#define PB_PT 4616

__global__ __launch_bounds__(256)
void prep_k(const float* __restrict__ x,   u16* __restrict__ xb,
            const float* __restrict__ w1w, u16* __restrict__ w1b16,
            const float* __restrict__ w2w, u16* __restrict__ w2b16,
            const float* __restrict__ d_w, const float* __restrict__ d_g,
            float* __restrict__ dwf,
            const float* __restrict__ p_w, const float* __restrict__ p_g,
            float* __restrict__ part, u16* __restrict__ pwT)
{
    const int bid = blockIdx.x;
    const int tid = threadIdx.x;

    if (bid < PB_W2) {
        const float* in;
        u16* out;
        int i;
        if (bid < PB_XB)      { in = x;   out = xb;    i = bid * 256 + tid; }
        else if (bid < PB_W1) { in = w1w; out = w1b16; i = (bid - PB_XB) * 256 + tid; }
        else                  { in = w2w; out = w2b16; i = (bid - PB_W1) * 256 + tid; }
        float4 v = ((const float4*)in)[i];
        ushort4v o;
        o.x = f2bf(v.x); o.y = f2bf(v.y); o.z = f2bf(v.z); o.w = f2bf(v.w);
        ((ushort4v*)out)[i] = o;
    } else if (bid < PB_DN) {
        __shared__ float red[KW][256];
        __shared__ float nrm[KW];
        const int b = bid - PB_W2;
        float s[KW];
#pragma unroll
        for (int k = 0; k < KW; k++) s[k] = 0.f;
        for (int c = tid; c < C_; c += 256) {
#pragma unroll
            for (int k = 0; k < KW; k++) {
                float v = d_w[((size_t)b * C_ + c) * KW + k];
                s[k] += v * v;
            }
        }
#pragma unroll
        for (int k = 0; k < KW; k++) red[k][tid] = s[k];
        __syncthreads();
        if (tid < KW) {
            float t = 0.f;
            for (int i = 0; i < 256; i++) t += red[tid][i];
            nrm[tid] = fmaxf(sqrtf(t), EPSF);
        }
        __syncthreads();
        for (int c = tid; c < C_; c += 256) {
            float g = d_g[(size_t)b * C_ + c];
#pragma unroll
            for (int k = 0; k < KW; k++)
                dwf[((size_t)b * C_ + c) * KW + k] =
                    d_w[((size_t)b * C_ + c) * KW + k] / nrm[k] * g;
        }
    } else {
        __shared__ float ts[64][65];
        __shared__ float sq[4][64];
        const int idx = bid - PB_DN;
        const int b   = idx >> 8;
        const int rem = idx & 255;
        const int c0  = (rem >> 4) * 64, o0 = (rem & 15) * 64;
        const int col = tid & 63;
        const int rg  = tid >> 6;
        float ssq = 0.f;
        for (int r = rg; r < 64; r += 4) {
            float v = p_w[((size_t)b * C_ + c0 + r) * O_ + o0 + col];
            ssq += v * v;
            ts[r][col] = v * p_g[(size_t)b * C_ + c0 + r];
        }
        sq[rg][col] = ssq;
        __syncthreads();
        if (tid < 64)
            part[((size_t)b * 16 + (rem >> 4)) * O_ + o0 + tid] =
                sq[0][tid] + sq[1][tid] + sq[2][tid] + sq[3][tid];
        for (int r = rg; r < 64; r += 4)
            pwT[((size_t)b * O_ + o0 + r) * C_ + c0 + col] = f2bf(ts[col][r]);
    }
}

// ---------------- depthwise conv along t + transpose write -------------------
__global__ __launch_bounds__(256)
void dwconv_k(const u16* __restrict__ h, const float* __restrict__ dwf,
              const float* __restrict__ d_b, u16* __restrict__ y1gT)
{
    __shared__ u16 hs[64][74];
    const int b  = blockIdx.z;
    const int c0 = blockIdx.y * 64, t0 = blockIdx.x * 64;
    const int tid = threadIdx.x;
    for (int idx = tid; idx < 64 * 72; idx += 256) {
        int cc = idx / 72, tt = idx % 72;
        int t = t0 + tt - 4;
        u16 v = 0;
        if (t >= 0 && t < T_) v = h[(size_t)(c0 + cc) * BT_ + b * T_ + t];
        hs[cc][tt] = v;
    }
    __syncthreads();
    const int cc = tid & 63;
    const int c  = c0 + cc;
    float w[KW];
#pragma unroll
    for (int k = 0; k < KW; k++) w[k] = dwf[((size_t)b * C_ + c) * KW + k];
    const float bb = d_b[(size_t)b * C_ + c];
    for (int tt = tid >> 6; tt < 64; tt += 4) {
        float s = bb;
#pragma unroll
        for (int k = 0; k < KW; k++) s += bf2f(hs[cc][tt + k]) * w[k];
        y1gT[((size_t)b * T_ + t0 + tt) * C_ + c] = f2bf(s);
    }
}

// ===== GEMM: 128 x (TNF*32) tile, BK=32, 3-buf LDS, counted-vmcnt pipeline ==
// T4 counted vmcnt: stage kt+1 stays in flight across the barrier.
// LDS swizzle key = (row>>1)&3 (NOT row&3): rows stride 64B = 16 banks, so
// bank-half is row&1; spreading the 8 same-half rows needs row bits 1-2.
// -> 2 rows/slot = 2-way = free (m136). Old key row&3 gave 4-way (1.58x).
// EPI 0: D(bf16) = mish(v + bias[row])
// EPI 1: D(bf16) = v*inv(part,col) + bias[col]   (per-batch Bt/bias/extra)
// EPI 2: D(f32)  = v + bias[col] + X[row,col]
template<int EPI, int TNF>
__device__ __forceinline__ void gemm_body(
    const u16* __restrict__ A, const u16* __restrict__ Bt,
    void* __restrict__ Dv, const float* __restrict__ bias,
    const float* __restrict__ extra, int M, int N, int Kd)
{
    __shared__ u16 As[3 * 4096];
    __shared__ u16 Bs[3 * 1024 * TNF];

    const int gx = gridDim.x;
    const unsigned nwg = (unsigned)gx * gridDim.y;
    unsigned lin = blockIdx.y * gx + blockIdx.x;
    lin = (lin & 7u) * (nwg >> 3) + (lin >> 3);
    const int m0 = (int)(lin / gx) * 128;
    const int n0 = (int)(lin % gx) * (TNF * 32);

    const int b = (EPI == 1) ? (m0 >> 10) : 0;
    if (EPI == 1) {
        Bt    += (size_t)b * O_ * C_;
        bias  += (size_t)b * O_;
        extra += (size_t)b * 16 * O_;
    }
    u16*   Db = (EPI == 2) ? nullptr : (u16*)Dv;
    float* Df = (EPI == 2) ? (float*)Dv : nullptr;
    const float* X = (EPI == 2) ? extra : nullptr;

    const int tid  = threadIdx.x;
    const int lane = tid & 63, wave = tid >> 6;
    const int wm = (wave & 1) * 64, wn = (wave >> 1) * (TNF * 16);
    const int lr = lane & 15;
    const int q  = lane >> 4;                             // 16B col slot 0..3
    const int srow  = lane >> 2;                          // 0..15 in chunk
    const int scolE = ((lane & 3) ^ ((lane >> 3) & 3)) * 8; // src col, key=(srow>>1)&3
    const int sw    = (q ^ ((lr >> 1) & 3)) << 3;           // swizzled read offset

    f32x4 acc[4][TNF];
#pragma unroll
    for (int i = 0; i < 4; i++)
#pragma unroll
        for (int j = 0; j < TNF; j++) acc[i][j] = (f32x4){0.f, 0.f, 0.f, 0.f};

    auto STAGE = [&](int buf, int kt) {
        const int k0 = kt << 5;
#pragma unroll
        for (int i = 0; i < 2; i++)
            GLOAD_LDS16(&A[(size_t)(m0 + i * 64 + wave * 16 + srow) * Kd + k0 + scolE],
                        &As[buf * 4096 + (i * 64 + wave * 16) * 32]);
#pragma unroll
        for (int i = 0; i < TNF / 2; i++)
            GLOAD_LDS16(&Bt[(size_t)(n0 + i * 64 + wave * 16 + srow) * Kd + k0 + scolE],
                        &Bs[buf * (1024 * TNF) + (i * 64 + wave * 16) * 32]);
    };

    const int NT = Kd >> 5;
    STAGE(0, 0);
    STAGE(1, 1);
    int rb = 0, sb = 2;
    for (int kt = 0; kt < NT; kt++) {
        if (kt == NT - 1) {
            asm volatile("s_waitcnt vmcnt(0)" ::: "memory");
        } else if constexpr (TNF == 4) {
            asm volatile("s_waitcnt vmcnt(4)" ::: "memory");
        } else {
            asm volatile("s_waitcnt vmcnt(3)" ::: "memory");
        }
        __builtin_amdgcn_s_barrier();
        if (kt + 2 < NT) STAGE(sb, kt + 2);
        const u16* as = &As[rb * 4096];
        const u16* bs = &Bs[rb * (1024 * TNF)];
        bf16x8 av[4], bv[TNF];
#pragma unroll
        for (int i = 0; i < 4; i++)
            av[i] = *(const bf16x8*)&as[(wm + i * 16 + lr) * 32 + sw];
#pragma unroll
        for (int j = 0; j < TNF; j++)
            bv[j] = *(const bf16x8*)&bs[(wn + j * 16 + lr) * 32 + sw];
#pragma unroll
        for (int i = 0; i < 4; i++)
#pragma unroll
            for (int j = 0; j < TNF; j++)
                acc[i][j] = __builtin_amdgcn_mfma_f32_16x16x32_bf16(
                    av[i], bv[j], acc[i][j], 0, 0, 0);
        rb = (rb == 2) ? 0 : rb + 1;
        sb = (sb == 2) ? 0 : sb + 1;
    }

    const int r0 = (lane >> 4) * 4;
#pragma unroll
    for (int i = 0; i < 4; i++) {
#pragma unroll
        for (int j = 0; j < TNF; j++) {
            const int col = n0 + wn + j * 16 + lr;
            float iv = 0.f;
            if (EPI == 1) {
                float s = 0.f;
#pragma unroll
                for (int ch = 0; ch < 16; ch++)
                    s += extra[(size_t)ch * O_ + col];
                iv = 1.f / fmaxf(sqrtf(s), EPSF);
            }
#pragma unroll
            for (int r = 0; r < 4; r++) {
                const int row = m0 + wm + i * 16 + r0 + r;
                float v = acc[i][j][r];
                if (EPI == 0) {
                    v += bias[row];
                    v = mishf(v);
                    Db[(size_t)row * N + col] = f2bf(v);
                } else if (EPI == 1) {
                    v = v * iv + bias[col];
                    Db[(size_t)row * N + col] = f2bf(v);
                } else {
                    v += bias[col] + X[(size_t)row * N + col];
                    Df[(size_t)row * N + col] = v;
                }
            }
        }
    }
}

__global__ __launch_bounds__(256, 3)
void gemm1_k(const u16* __restrict__ A, const u16* __restrict__ Bt,
             u16* __restrict__ D, const float* __restrict__ bias,
             int M, int N, int Kd)
{
    gemm_body<0, 4>(A, Bt, D, bias, nullptr, M, N, Kd);
}

__global__ __launch_bounds__(256, 3)
void gemm2_k(const u16* __restrict__ A, const u16* __restrict__ Bt,
             u16* __restrict__ D, const float* __restrict__ bias,
             const float* __restrict__ extra, int M, int N, int Kd)
{
    gemm_body<1, 4>(A, Bt, D, bias, extra, M, N, Kd);
}

__global__ __launch_bounds__(256, 3)
void gemm3_k(const u16* __restrict__ A, const u16* __restrict__ Bt,
             float* __restrict__ D, const float* __restrict__ bias,
             const float* __restrict__ X, int M, int N, int Kd)
{
    gemm_body<2, 2>(A, Bt, (void*)D, bias, X, M, N, Kd);
}

extern "C" void kernel_launch(void* const* d_in, const int* in_sizes, int n_in,
                              void* d_out, int out_size, void* d_ws, size_t ws_size,
                              hipStream_t stream)
{
    const float* x   = (const float*)d_in[0];
    const float* d_w = (const float*)d_in[1];
    const float* d_g = (const float*)d_in[2];
    const float* d_b = (const float*)d_in[3];
    const float* p_w = (const float*)d_in[4];
    const float* p_g = (const float*)d_in[5];
    const float* p_b = (const float*)d_in[6];
    const float* w1w = (const float*)d_in[7];
    const float* w1b = (const float*)d_in[8];
    const float* w2w = (const float*)d_in[9];
    const float* w2b = (const float*)d_in[10];
    float* out = (float*)d_out;

    char* ws = (char*)d_ws;
    const size_t SZ = (size_t)16777216;           // 16 MB
    u16*   h    = (u16*)(ws);                     // [C][B*T] bf16
    u16*   y1gT = (u16*)(ws + SZ);                // [B*T][C] bf16
    u16*   pwT  = (u16*)(ws + 2 * SZ);            // [B][O][C] bf16
    u16*   y2T  = (u16*)(ws + 3 * SZ);            // [B*T][O] bf16
    u16*   xb   = (u16*)(ws + 4 * SZ);            // [B*T][DI] bf16 (4 MB)
    u16*   w1b16= (u16*)(ws + 4 * SZ + 4194304);  // [C][DI] bf16
    u16*   w2b16= (u16*)(ws + 4 * SZ + 4718592);  // [DI][O] bf16
    float* dwf  = (float*)(ws + 4 * SZ + 5242880);           // B*C*KW f32
    float* part = (float*)(ws + 4 * SZ + 5242880 + 294912);  // B*16*O f32

    prep_k<<<dim3(PB_PT), 256, 0, stream>>>(
        x, xb, w1w, w1b16, w2w, w2b16, d_w, d_g, dwf, p_w, p_g, part, pwT);

    // GEMM1: h[c][bt] = mish(w1[c,:] . xb[bt,:] + w1b[c]);  M=C, N=B*T, K=DI
    gemm1_k<<<dim3(BT_ / 128, C_ / 128), 256, 0, stream>>>(
        w1b16, xb, h, w1b, C_, BT_, DI_);

    dwconv_k<<<dim3(T_ / 64, C_ / 64, B_), 256, 0, stream>>>(h, dwf, d_b, y1gT);

    // GEMM2: y2T[bt][o] = (y1gT[bt,:] . pwT[b][o,:])*inv[b][o] + p_b[b][o]
    gemm2_k<<<dim3(O_ / 128, BT_ / 128), 256, 0, stream>>>(
        y1gT, pwT, y2T, p_b, part, BT_, O_, C_);

    // GEMM3: out[bt][i] = y2T[bt,:] . w2[i,:] + w2b[i] + x[bt][i];  N=DI
    gemm3_k<<<dim3(DI_ / 64, BT_ / 128), 256, 0, stream>>>(
        y2T, w2b16, out, w2b, x, BT_, DI_, O_);
}

// Round 10
// 105.860 us; speedup vs baseline: 1.1239x; 1.0014x over previous
//
#include <hip/hip_runtime.h>
#include <hip/hip_bf16.h>

#define B_  8
#define T_  1024
#define DI_ 256
#define C_  1024
#define O_  1024
#define KW  9
#define BT_ 8192
#define EPSF 1e-12f

typedef unsigned short u16;
typedef u16   ushort8 __attribute__((ext_vector_type(8)));
typedef u16   ushort4v __attribute__((ext_vector_type(4)));
typedef __bf16 bf16x8 __attribute__((ext_vector_type(8)));
typedef float  f32x4  __attribute__((ext_vector_type(4)));

#define GLOAD_LDS16(g, l) __builtin_amdgcn_global_load_lds( \
    (const __attribute__((address_space(1))) void*)(g),      \
    (__attribute__((address_space(3))) void*)(l), 16, 0, 0)

__device__ __forceinline__ float bf2f(u16 u) {
    union { unsigned int i; float f; } z; z.i = ((unsigned int)u) << 16; return z.f;
}
__device__ __forceinline__ u16 f2bf(float f) {
    union { float f; unsigned int i; } z; z.f = f;
    unsigned int i = z.i;
    i += 0x7FFFu + ((i >> 16) & 1u);   // RNE
    return (u16)(i >> 16);
}
__device__ __forceinline__ float mishf(float v) {
    float u = __expf(v);
    float w = 1.f + u;
    return v * (1.f - 2.f / (w * w + 1.f));
}

// ================= mega prep kernel =========================================
#define PB_XB 2048
#define PB_W1 2304
#define PB_W2 2560
#define PB_DN 2568
#define PB_PT 4616

__global__ __launch_bounds__(256)
void prep_k(const float* __restrict__ x,   u16* __restrict__ xb,
            const float* __restrict__ w1w, u16* __restrict__ w1b16,
            const float* __restrict__ w2w, u16* __restrict__ w2b16,
            const float* __restrict__ d_w, const float* __restrict__ d_g,
            float* __restrict__ dwf,
            const float* __restrict__ p_w, const float* __restrict__ p_g,
            float* __restrict__ part, u16* __restrict__ pwT)
{
    const int bid = blockIdx.x;
    const int tid = threadIdx.x;

    if (bid < PB_W2) {
        const float* in;
        u16* out;
        int i;
        if (bid < PB_XB)      { in = x;   out = xb;    i = bid * 256 + tid; }
        else if (bid < PB_W1) { in = w1w; out = w1b16; i = (bid - PB_XB) * 256 + tid; }
        else                  { in = w2w; out = w2b16; i = (bid - PB_W1) * 256 + tid; }
        float4 v = ((const float4*)in)[i];
        ushort4v o;
        o.x = f2bf(v.x); o.y = f2bf(v.y); o.z = f2bf(v.z); o.w = f2bf(v.w);
        ((ushort4v*)out)[i] = o;
    } else if (bid < PB_DN) {
        __shared__ float red[KW][256];
        __shared__ float nrm[KW];
        const int b = bid - PB_W2;
        float s[KW];
#pragma unroll
        for (int k = 0; k < KW; k++) s[k] = 0.f;
        for (int c = tid; c < C_; c += 256) {
#pragma unroll
            for (int k = 0; k < KW; k++) {
                float v = d_w[((size_t)b * C_ + c) * KW + k];
                s[k] += v * v;
            }
        }
#pragma unroll
        for (int k = 0; k < KW; k++) red[k][tid] = s[k];
        __syncthreads();
        if (tid < KW) {
            float t = 0.f;
            for (int i = 0; i < 256; i++) t += red[tid][i];
            nrm[tid] = fmaxf(sqrtf(t), EPSF);
        }
        __syncthreads();
        for (int c = tid; c < C_; c += 256) {
            float g = d_g[(size_t)b * C_ + c];
#pragma unroll
            for (int k = 0; k < KW; k++)
                dwf[((size_t)b * C_ + c) * KW + k] =
                    d_w[((size_t)b * C_ + c) * KW + k] / nrm[k] * g;
        }
    } else {
        __shared__ float ts[64][65];
        __shared__ float sq[4][64];
        const int idx = bid - PB_DN;
        const int b   = idx >> 8;
        const int rem = idx & 255;
        const int c0  = (rem >> 4) * 64, o0 = (rem & 15) * 64;
        const int col = tid & 63;
        const int rg  = tid >> 6;
        float ssq = 0.f;
        for (int r = rg; r < 64; r += 4) {
            float v = p_w[((size_t)b * C_ + c0 + r) * O_ + o0 + col];
            ssq += v * v;
            ts[r][col] = v * p_g[(size_t)b * C_ + c0 + r];
        }
        sq[rg][col] = ssq;
        __syncthreads();
        if (tid < 64)
            part[((size_t)b * 16 + (rem >> 4)) * O_ + o0 + tid] =
                sq[0][tid] + sq[1][tid] + sq[2][tid] + sq[3][tid];
        for (int r = rg; r < 64; r += 4)
            pwT[((size_t)b * O_ + o0 + r) * C_ + c0 + col] = f2bf(ts[col][r]);
    }
}

// ---------------- depthwise conv along t + transpose write -------------------
__global__ __launch_bounds__(256)
void dwconv_k(const u16* __restrict__ h, const float* __restrict__ dwf,
              const float* __restrict__ d_b, u16* __restrict__ y1gT)
{
    __shared__ u16 hs[64][74];
    const int b  = blockIdx.z;
    const int c0 = blockIdx.y * 64, t0 = blockIdx.x * 64;
    const int tid = threadIdx.x;
    for (int idx = tid; idx < 64 * 72; idx += 256) {
        int cc = idx / 72, tt = idx % 72;
        int t = t0 + tt - 4;
        u16 v = 0;
        if (t >= 0 && t < T_) v = h[(size_t)(c0 + cc) * BT_ + b * T_ + t];
        hs[cc][tt] = v;
    }
    __syncthreads();
    const int cc = tid & 63;
    const int c  = c0 + cc;
    float w[KW];
#pragma unroll
    for (int k = 0; k < KW; k++) w[k] = dwf[((size_t)b * C_ + c) * KW + k];
    const float bb = d_b[(size_t)b * C_ + c];
    for (int tt = tid >> 6; tt < 64; tt += 4) {
        float s = bb;
#pragma unroll
        for (int k = 0; k < KW; k++) s += bf2f(hs[cc][tt + k]) * w[k];
        y1gT[((size_t)b * T_ + t0 + tt) * C_ + c] = f2bf(s);
    }
}

// ===== GEMM: 2-wave blocks, BM=64 x BN=TNF*32, wave tile 64x(TNF*16) ========
// BK=32, 3-buf LDS (36KB @TNF=4), counted-vmcnt depth-2 pipeline,
// 4 blocks/CU resident -> cross-block overlap fills barrier/lat holes.
// Swizzle key (row>>1)&3 both sides (bank-conflict-free, verified r9).
// EPI 0: D(bf16) = mish(v + bias[row])
// EPI 1: D(bf16) = v*inv(part,col) + bias[col]   (per-batch Bt/bias/extra)
// EPI 2: D(f32)  = v + bias[col] + X[row,col]
template<int EPI, int TNF>
__device__ __forceinline__ void gemm_body(
    const u16* __restrict__ A, const u16* __restrict__ Bt,
    void* __restrict__ Dv, const float* __restrict__ bias,
    const float* __restrict__ extra, int M, int N, int Kd)
{
    __shared__ u16 As[3 * 2048];
    __shared__ u16 Bs[3 * TNF * 1024];

    const int gx = gridDim.x;
    const unsigned nwg = (unsigned)gx * gridDim.y;
    unsigned lin = blockIdx.y * gx + blockIdx.x;
    lin = (lin & 7u) * (nwg >> 3) + (lin >> 3);
    const int m0 = (int)(lin / gx) * 64;
    const int n0 = (int)(lin % gx) * (TNF * 32);

    const int b = (EPI == 1) ? (m0 >> 10) : 0;
    if (EPI == 1) {
        Bt    += (size_t)b * O_ * C_;
        bias  += (size_t)b * O_;
        extra += (size_t)b * 16 * O_;
    }
    u16*   Db = (EPI == 2) ? nullptr : (u16*)Dv;
    float* Df = (EPI == 2) ? (float*)Dv : nullptr;
    const float* X = (EPI == 2) ? extra : nullptr;

    const int tid  = threadIdx.x;
    const int lane = tid & 63, wave = tid >> 6;        // wave 0..1
    const int wn = wave * (TNF * 16);
    const int lr = lane & 15;
    const int q  = lane >> 4;                              // 16B col slot
    const int srow  = lane >> 2;                           // 0..15 in chunk
    const int scolE = ((lane & 3) ^ ((lane >> 3) & 3)) * 8; // src col swizzled
    const int sw    = (q ^ ((lr >> 1) & 3)) << 3;           // read swizzle

    f32x4 acc[4][TNF];
#pragma unroll
    for (int i = 0; i < 4; i++)
#pragma unroll
        for (int j = 0; j < TNF; j++) acc[i][j] = (f32x4){0.f, 0.f, 0.f, 0.f};

    auto STAGE = [&](int buf, int kt) {
        const int k0 = kt << 5;
#pragma unroll
        for (int i = 0; i < 2; i++)
            GLOAD_LDS16(&A[(size_t)(m0 + wave * 32 + i * 16 + srow) * Kd + k0 + scolE],
                        &As[buf * 2048 + (wave * 32 + i * 16) * 32]);
#pragma unroll
        for (int i = 0; i < TNF; i++)
            GLOAD_LDS16(&Bt[(size_t)(n0 + wave * TNF * 16 + i * 16 + srow) * Kd + k0 + scolE],
                        &Bs[buf * (TNF * 1024) + (wave * TNF * 16 + i * 16) * 32]);
    };

    const int NT = Kd >> 5;
    STAGE(0, 0);
    STAGE(1, 1);
    int rb = 0, sb = 2;
    for (int kt = 0; kt < NT; kt++) {
        if (kt == NT - 1) {
            asm volatile("s_waitcnt vmcnt(0)" ::: "memory");
        } else if constexpr (TNF == 4) {
            asm volatile("s_waitcnt vmcnt(6)" ::: "memory");
        } else {
            asm volatile("s_waitcnt vmcnt(4)" ::: "memory");
        }
        __builtin_amdgcn_s_barrier();
        if (kt + 2 < NT) STAGE(sb, kt + 2);
        const u16* as = &As[rb * 2048];
        const u16* bs = &Bs[rb * (TNF * 1024)];
        bf16x8 av[4], bv[TNF];
#pragma unroll
        for (int i = 0; i < 4; i++)
            av[i] = *(const bf16x8*)&as[(i * 16 + lr) * 32 + sw];
#pragma unroll
        for (int j = 0; j < TNF; j++)
            bv[j] = *(const bf16x8*)&bs[(wn + j * 16 + lr) * 32 + sw];
        __builtin_amdgcn_s_setprio(1);
#pragma unroll
        for (int i = 0; i < 4; i++)
#pragma unroll
            for (int j = 0; j < TNF; j++)
                acc[i][j] = __builtin_amdgcn_mfma_f32_16x16x32_bf16(
                    av[i], bv[j], acc[i][j], 0, 0, 0);
        __builtin_amdgcn_s_setprio(0);
        rb = (rb == 2) ? 0 : rb + 1;
        sb = (sb == 2) ? 0 : sb + 1;
    }

    const int r0 = (lane >> 4) * 4;
#pragma unroll
    for (int i = 0; i < 4; i++) {
#pragma unroll
        for (int j = 0; j < TNF; j++) {
            const int col = n0 + wn + j * 16 + lr;
            float iv = 0.f;
            if (EPI == 1) {
                float s = 0.f;
#pragma unroll
                for (int ch = 0; ch < 16; ch++)
                    s += extra[(size_t)ch * O_ + col];
                iv = 1.f / fmaxf(sqrtf(s), EPSF);
            }
#pragma unroll
            for (int r = 0; r < 4; r++) {
                const int row = m0 + i * 16 + r0 + r;
                float v = acc[i][j][r];
                if (EPI == 0) {
                    v += bias[row];
                    v = mishf(v);
                    Db[(size_t)row * N + col] = f2bf(v);
                } else if (EPI == 1) {
                    v = v * iv + bias[col];
                    Db[(size_t)row * N + col] = f2bf(v);
                } else {
                    v += bias[col] + X[(size_t)row * N + col];
                    Df[(size_t)row * N + col] = v;
                }
            }
        }
    }
}

__global__ __launch_bounds__(128, 2)
void gemm1_k(const u16* __restrict__ A, const u16* __restrict__ Bt,
             u16* __restrict__ D, const float* __restrict__ bias,
             int M, int N, int Kd)
{
    gemm_body<0, 4>(A, Bt, D, bias, nullptr, M, N, Kd);
}

__global__ __launch_bounds__(128, 2)
void gemm2_k(const u16* __restrict__ A, const u16* __restrict__ Bt,
             u16* __restrict__ D, const float* __restrict__ bias,
             const float* __restrict__ extra, int M, int N, int Kd)
{
    gemm_body<1, 4>(A, Bt, D, bias, extra, M, N, Kd);
}

__global__ __launch_bounds__(128, 2)
void gemm3_k(const u16* __restrict__ A, const u16* __restrict__ Bt,
             float* __restrict__ D, const float* __restrict__ bias,
             const float* __restrict__ X, int M, int N, int Kd)
{
    gemm_body<2, 2>(A, Bt, (void*)D, bias, X, M, N, Kd);
}

extern "C" void kernel_launch(void* const* d_in, const int* in_sizes, int n_in,
                              void* d_out, int out_size, void* d_ws, size_t ws_size,
                              hipStream_t stream)
{
    const float* x   = (const float*)d_in[0];
    const float* d_w = (const float*)d_in[1];
    const float* d_g = (const float*)d_in[2];
    const float* d_b = (const float*)d_in[3];
    const float* p_w = (const float*)d_in[4];
    const float* p_g = (const float*)d_in[5];
    const float* p_b = (const float*)d_in[6];
    const float* w1w = (const float*)d_in[7];
    const float* w1b = (const float*)d_in[8];
    const float* w2w = (const float*)d_in[9];
    const float* w2b = (const float*)d_in[10];
    float* out = (float*)d_out;

    char* ws = (char*)d_ws;
    const size_t SZ = (size_t)16777216;           // 16 MB
    u16*   h    = (u16*)(ws);                     // [C][B*T] bf16
    u16*   y1gT = (u16*)(ws + SZ);                // [B*T][C] bf16
    u16*   pwT  = (u16*)(ws + 2 * SZ);            // [B][O][C] bf16
    u16*   y2T  = (u16*)(ws + 3 * SZ);            // [B*T][O] bf16
    u16*   xb   = (u16*)(ws + 4 * SZ);            // [B*T][DI] bf16 (4 MB)
    u16*   w1b16= (u16*)(ws + 4 * SZ + 4194304);  // [C][DI] bf16
    u16*   w2b16= (u16*)(ws + 4 * SZ + 4718592);  // [DI][O] bf16
    float* dwf  = (float*)(ws + 4 * SZ + 5242880);           // B*C*KW f32
    float* part = (float*)(ws + 4 * SZ + 5242880 + 294912);  // B*16*O f32

    prep_k<<<dim3(PB_PT), 256, 0, stream>>>(
        x, xb, w1w, w1b16, w2w, w2b16, d_w, d_g, dwf, p_w, p_g, part, pwT);

    // GEMM1: h[c][bt] = mish(w1[c,:] . xb[bt,:] + w1b[c]);  M=C, N=B*T, K=DI
    gemm1_k<<<dim3(BT_ / 128, C_ / 64), 128, 0, stream>>>(
        w1b16, xb, h, w1b, C_, BT_, DI_);

    dwconv_k<<<dim3(T_ / 64, C_ / 64, B_), 256, 0, stream>>>(h, dwf, d_b, y1gT);

    // GEMM2: y2T[bt][o] = (y1gT[bt,:] . pwT[b][o,:])*inv[b][o] + p_b[b][o]
    gemm2_k<<<dim3(O_ / 128, BT_ / 64), 128, 0, stream>>>(
        y1gT, pwT, y2T, p_b, part, BT_, O_, C_);

    // GEMM3: out[bt][i] = y2T[bt,:] . w2[i,:] + w2b[i] + x[bt][i];  N=DI
    gemm3_k<<<dim3(DI_ / 64, BT_ / 64), 128, 0, stream>>>(
        y2T, w2b16, out, w2b, x, BT_, DI_, O_);
}

// Round 11
// 103.983 us; speedup vs baseline: 1.1442x; 1.0180x over previous
//
#include <hip/hip_runtime.h>
#include <hip/hip_bf16.h>

#define B_  8
#define T_  1024
#define DI_ 256
#define C_  1024
#define O_  1024
#define KW  9
#define BT_ 8192
#define EPSF 1e-12f

typedef unsigned short u16;
typedef u16   ushort8 __attribute__((ext_vector_type(8)));
typedef u16   ushort4v __attribute__((ext_vector_type(4)));
typedef __bf16 bf16x8 __attribute__((ext_vector_type(8)));
typedef float  f32x4  __attribute__((ext_vector_type(4)));

#define GLOAD_LDS16(g, l) __builtin_amdgcn_global_load_lds( \
    (const __attribute__((address_space(1))) void*)(g),      \
    (__attribute__((address_space(3))) void*)(l), 16, 0, 0)

__device__ __forceinline__ float bf2f(u16 u) {
    union { unsigned int i; float f; } z; z.i = ((unsigned int)u) << 16; return z.f;
}
__device__ __forceinline__ u16 f2bf(float f) {
    union { float f; unsigned int i; } z; z.f = f;
    unsigned int i = z.i;
    i += 0x7FFFu + ((i >> 16) & 1u);   // RNE
    return (u16)(i >> 16);
}
__device__ __forceinline__ float mishf(float v) {
    float u = __expf(v);
    float w = 1.f + u;
    return v * (1.f - 2.f / (w * w + 1.f));
}

// ================= mega prep kernel =========================================
#define PB_XB 2048
#define PB_W1 2304
#define PB_W2 2560
#define PB_DN 2568
#define PB_PT 4616

__global__ __launch_bounds__(256)
void prep_k(const float* __restrict__ x,   u16* __restrict__ xb,
            const float* __restrict__ w1w, u16* __restrict__ w1b16,
            const float* __restrict__ w2w, u16* __restrict__ w2b16,
            const float* __restrict__ d_w, const float* __restrict__ d_g,
            float* __restrict__ dwf,
            const float* __restrict__ p_w, const float* __restrict__ p_g,
            float* __restrict__ part, u16* __restrict__ pwT)
{
    const int bid = blockIdx.x;
    const int tid = threadIdx.x;

    if (bid < PB_W2) {
        const float* in;
        u16* out;
        int i;
        if (bid < PB_XB)      { in = x;   out = xb;    i = bid * 256 + tid; }
        else if (bid < PB_W1) { in = w1w; out = w1b16; i = (bid - PB_XB) * 256 + tid; }
        else                  { in = w2w; out = w2b16; i = (bid - PB_W1) * 256 + tid; }
        float4 v = ((const float4*)in)[i];
        ushort4v o;
        o.x = f2bf(v.x); o.y = f2bf(v.y); o.z = f2bf(v.z); o.w = f2bf(v.w);
        ((ushort4v*)out)[i] = o;
    } else if (bid < PB_DN) {
        __shared__ float red[KW][256];
        __shared__ float nrm[KW];
        const int b = bid - PB_W2;
        float s[KW];
#pragma unroll
        for (int k = 0; k < KW; k++) s[k] = 0.f;
        for (int c = tid; c < C_; c += 256) {
#pragma unroll
            for (int k = 0; k < KW; k++) {
                float v = d_w[((size_t)b * C_ + c) * KW + k];
                s[k] += v * v;
            }
        }
#pragma unroll
        for (int k = 0; k < KW; k++) red[k][tid] = s[k];
        __syncthreads();
        if (tid < KW) {
            float t = 0.f;
            for (int i = 0; i < 256; i++) t += red[tid][i];
            nrm[tid] = fmaxf(sqrtf(t), EPSF);
        }
        __syncthreads();
        for (int c = tid; c < C_; c += 256) {
            float g = d_g[(size_t)b * C_ + c];
#pragma unroll
            for (int k = 0; k < KW; k++)
                dwf[((size_t)b * C_ + c) * KW + k] =
                    d_w[((size_t)b * C_ + c) * KW + k] / nrm[k] * g;
        }
    } else {
        __shared__ float ts[64][65];
        __shared__ float sq[4][64];
        const int idx = bid - PB_DN;
        const int b   = idx >> 8;
        const int rem = idx & 255;
        const int c0  = (rem >> 4) * 64, o0 = (rem & 15) * 64;
        const int col = tid & 63;
        const int rg  = tid >> 6;
        float ssq = 0.f;
        for (int r = rg; r < 64; r += 4) {
            float v = p_w[((size_t)b * C_ + c0 + r) * O_ + o0 + col];
            ssq += v * v;
            ts[r][col] = v * p_g[(size_t)b * C_ + c0 + r];
        }
        sq[rg][col] = ssq;
        __syncthreads();
        if (tid < 64)
            part[((size_t)b * 16 + (rem >> 4)) * O_ + o0 + tid] =
                sq[0][tid] + sq[1][tid] + sq[2][tid] + sq[3][tid];
        for (int r = rg; r < 64; r += 4)
            pwT[((size_t)b * O_ + o0 + r) * C_ + c0 + col] = f2bf(ts[col][r]);
    }
}

// ---------------- depthwise conv along t + transpose write -------------------
__global__ __launch_bounds__(256)
void dwconv_k(const u16* __restrict__ h, const float* __restrict__ dwf,
              const float* __restrict__ d_b, u16* __restrict__ y1gT)
{
    __shared__ u16 hs[64][74];
    const int b  = blockIdx.z;
    const int c0 = blockIdx.y * 64, t0 = blockIdx.x * 64;
    const int tid = threadIdx.x;
    for (int idx = tid; idx < 64 * 72; idx += 256) {
        int cc = idx / 72, tt = idx % 72;
        int t = t0 + tt - 4;
        u16 v = 0;
        if (t >= 0 && t < T_) v = h[(size_t)(c0 + cc) * BT_ + b * T_ + t];
        hs[cc][tt] = v;
    }
    __syncthreads();
    const int cc = tid & 63;
    const int c  = c0 + cc;
    float w[KW];
#pragma unroll
    for (int k = 0; k < KW; k++) w[k] = dwf[((size_t)b * C_ + c) * KW + k];
    const float bb = d_b[(size_t)b * C_ + c];
    for (int tt = tid >> 6; tt < 64; tt += 4) {
        float s = bb;
#pragma unroll
        for (int k = 0; k < KW; k++) s += bf2f(hs[cc][tt + k]) * w[k];
        y1gT[((size_t)b * T_ + t0 + tt) * C_ + c] = f2bf(s);
    }
}

// ===== big GEMM (GEMM1/2): 512 thr, BM=128 x BN=256, BK=64, 8 waves 64x64 ===
// 3-buf LDS (144 KB), counted-vmcnt depth-2 (T4), XCD swizzle (T1),
// XOR swizzle key row&7 over 8 16B-slots (conflict-free b128), setprio (T5).
// NT = Kd/64 iterations -> half the per-iter overhead of BK=32.
// EPI 0: D(bf16) = mish(v + bias[row])
// EPI 1: D(bf16) = v*inv(part,col) + bias[col]   (per-batch Bt/bias/extra)
template<int EPI>
__device__ __forceinline__ void gemm12_body(
    const u16* __restrict__ A, const u16* __restrict__ Bt,
    u16* __restrict__ Db, const float* __restrict__ bias,
    const float* __restrict__ extra, int M, int N, int Kd)
{
    __shared__ u16 As[3 * 128 * 64];   // 48 KB
    __shared__ u16 Bs[3 * 256 * 64];   // 96 KB

    const int gx = gridDim.x;
    const unsigned nwg = (unsigned)gx * gridDim.y;
    unsigned lin = blockIdx.y * gx + blockIdx.x;
    lin = (lin & 7u) * (nwg >> 3) + (lin >> 3);
    const int m0 = (int)(lin / gx) * 128;
    const int n0 = (int)(lin % gx) * 256;

    const int b = (EPI == 1) ? (m0 >> 10) : 0;
    if (EPI == 1) {
        Bt    += (size_t)b * O_ * C_;
        bias  += (size_t)b * O_;
        extra += (size_t)b * 16 * O_;
    }

    const int tid  = threadIdx.x;              // 0..511
    const int lane = tid & 63, wave = tid >> 6; // 8 waves
    const int wm = (wave >> 2) * 64, wn = (wave & 3) * 64;
    const int lr = lane & 15;
    // staging: 512 thr x 16B = one 64-row x 128B chunk per instruction
    const int srow8 = tid >> 3;                            // row in chunk
    const int scolE = ((tid & 7) ^ ((tid >> 3) & 7)) * 8;  // swizzled src slot

    f32x4 acc[4][4];
#pragma unroll
    for (int i = 0; i < 4; i++)
#pragma unroll
        for (int j = 0; j < 4; j++) acc[i][j] = (f32x4){0.f, 0.f, 0.f, 0.f};

    auto STAGE = [&](int buf, int kt) {
        const int k0 = kt << 6;
#pragma unroll
        for (int i = 0; i < 2; i++)
            GLOAD_LDS16(&A[(size_t)(m0 + i * 64 + srow8) * Kd + k0 + scolE],
                        &As[buf * 8192 + (i * 64 + wave * 8) * 64]);
#pragma unroll
        for (int i = 0; i < 4; i++)
            GLOAD_LDS16(&Bt[(size_t)(n0 + i * 64 + srow8) * Kd + k0 + scolE],
                        &Bs[buf * 16384 + (i * 64 + wave * 8) * 64]);
    };

    const int NT = Kd >> 6;
    STAGE(0, 0);
    STAGE(1, 1);
    int rb = 0, sb = 2;
    for (int kt = 0; kt < NT; kt++) {
        if (kt == NT - 1) {
            asm volatile("s_waitcnt vmcnt(0)" ::: "memory");
        } else {
            asm volatile("s_waitcnt vmcnt(6)" ::: "memory");
        }
        __builtin_amdgcn_s_barrier();
        if (kt + 2 < NT) STAGE(sb, kt + 2);
        const u16* as = &As[rb * 8192];
        const u16* bs = &Bs[rb * 16384];
        bf16x8 av[2][4], bv[2][4];
#pragma unroll
        for (int kk = 0; kk < 2; kk++) {
            const int q  = (lane >> 4) + kk * 4;           // 16B slot 0..7
            const int sw = (q ^ (lr & 7)) << 3;
#pragma unroll
            for (int i = 0; i < 4; i++)
                av[kk][i] = *(const bf16x8*)&as[(wm + i * 16 + lr) * 64 + sw];
#pragma unroll
            for (int j = 0; j < 4; j++)
                bv[kk][j] = *(const bf16x8*)&bs[(wn + j * 16 + lr) * 64 + sw];
        }
        __builtin_amdgcn_s_setprio(1);
#pragma unroll
        for (int kk = 0; kk < 2; kk++)
#pragma unroll
            for (int i = 0; i < 4; i++)
#pragma unroll
                for (int j = 0; j < 4; j++)
                    acc[i][j] = __builtin_amdgcn_mfma_f32_16x16x32_bf16(
                        av[kk][i], bv[kk][j], acc[i][j], 0, 0, 0);
        __builtin_amdgcn_s_setprio(0);
        rb = (rb == 2) ? 0 : rb + 1;
        sb = (sb == 2) ? 0 : sb + 1;
    }

    const int r0 = (lane >> 4) * 4;
#pragma unroll
    for (int i = 0; i < 4; i++) {
#pragma unroll
        for (int j = 0; j < 4; j++) {
            const int col = n0 + wn + j * 16 + lr;
            float iv = 0.f;
            if (EPI == 1) {
                float s = 0.f;
#pragma unroll
                for (int ch = 0; ch < 16; ch++)
                    s += extra[(size_t)ch * O_ + col];
                iv = 1.f / fmaxf(sqrtf(s), EPSF);
            }
#pragma unroll
            for (int r = 0; r < 4; r++) {
                const int row = m0 + wm + i * 16 + r0 + r;
                float v = acc[i][j][r];
                if (EPI == 0) {
                    v += bias[row];
                    v = mishf(v);
                } else {
                    v = v * iv + bias[col];
                }
                Db[(size_t)row * N + col] = f2bf(v);
            }
        }
    }
}

__global__ __launch_bounds__(512, 2)
void gemm1_k(const u16* __restrict__ A, const u16* __restrict__ Bt,
             u16* __restrict__ D, const float* __restrict__ bias,
             int M, int N, int Kd)
{
    gemm12_body<0>(A, Bt, D, bias, nullptr, M, N, Kd);
}

__global__ __launch_bounds__(512, 2)
void gemm2_k(const u16* __restrict__ A, const u16* __restrict__ Bt,
             u16* __restrict__ D, const float* __restrict__ bias,
             const float* __restrict__ extra, int M, int N, int Kd)
{
    gemm12_body<1>(A, Bt, D, bias, extra, M, N, Kd);
}

// ============ GEMM3: 2-wave 64x64 tile, BK=32, 3-buf (memory-bound) =========
__global__ __launch_bounds__(128, 2)
void gemm3_k(const u16* __restrict__ A, const u16* __restrict__ Bt,
             float* __restrict__ Df, const float* __restrict__ bias,
             const float* __restrict__ X, int M, int N, int Kd)
{
    __shared__ u16 As[3 * 2048];
    __shared__ u16 Bs[3 * 2048];

    const int gx = gridDim.x;
    const unsigned nwg = (unsigned)gx * gridDim.y;
    unsigned lin = blockIdx.y * gx + blockIdx.x;
    lin = (lin & 7u) * (nwg >> 3) + (lin >> 3);
    const int m0 = (int)(lin / gx) * 64;
    const int n0 = (int)(lin % gx) * 64;

    const int tid  = threadIdx.x;
    const int lane = tid & 63, wave = tid >> 6;
    const int wn = wave * 32;
    const int lr = lane & 15;
    const int q  = lane >> 4;
    const int srow  = lane >> 2;
    const int scolE = ((lane & 3) ^ ((lane >> 3) & 3)) * 8;
    const int sw    = (q ^ ((lr >> 1) & 3)) << 3;

    f32x4 acc[4][2];
#pragma unroll
    for (int i = 0; i < 4; i++)
#pragma unroll
        for (int j = 0; j < 2; j++) acc[i][j] = (f32x4){0.f, 0.f, 0.f, 0.f};

    auto STAGE = [&](int buf, int kt) {
        const int k0 = kt << 5;
#pragma unroll
        for (int i = 0; i < 2; i++)
            GLOAD_LDS16(&A[(size_t)(m0 + wave * 32 + i * 16 + srow) * Kd + k0 + scolE],
                        &As[buf * 2048 + (wave * 32 + i * 16) * 32]);
#pragma unroll
        for (int i = 0; i < 2; i++)
            GLOAD_LDS16(&Bt[(size_t)(n0 + wave * 32 + i * 16 + srow) * Kd + k0 + scolE],
                        &Bs[buf * 2048 + (wave * 32 + i * 16) * 32]);
    };

    const int NT = Kd >> 5;
    STAGE(0, 0);
    STAGE(1, 1);
    int rb = 0, sb = 2;
    for (int kt = 0; kt < NT; kt++) {
        if (kt == NT - 1) {
            asm volatile("s_waitcnt vmcnt(0)" ::: "memory");
        } else {
            asm volatile("s_waitcnt vmcnt(4)" ::: "memory");
        }
        __builtin_amdgcn_s_barrier();
        if (kt + 2 < NT) STAGE(sb, kt + 2);
        const u16* as = &As[rb * 2048];
        const u16* bs = &Bs[rb * 2048];
        bf16x8 av[4], bv[2];
#pragma unroll
        for (int i = 0; i < 4; i++)
            av[i] = *(const bf16x8*)&as[(i * 16 + lr) * 32 + sw];
#pragma unroll
        for (int j = 0; j < 2; j++)
            bv[j] = *(const bf16x8*)&bs[(wn + j * 16 + lr) * 32 + sw];
        __builtin_amdgcn_s_setprio(1);
#pragma unroll
        for (int i = 0; i < 4; i++)
#pragma unroll
            for (int j = 0; j < 2; j++)
                acc[i][j] = __builtin_amdgcn_mfma_f32_16x16x32_bf16(
                    av[i], bv[j], acc[i][j], 0, 0, 0);
        __builtin_amdgcn_s_setprio(0);
        rb = (rb == 2) ? 0 : rb + 1;
        sb = (sb == 2) ? 0 : sb + 1;
    }

    const int r0 = (lane >> 4) * 4;
#pragma unroll
    for (int i = 0; i < 4; i++) {
#pragma unroll
        for (int j = 0; j < 2; j++) {
            const int col = n0 + wn + j * 16 + lr;
#pragma unroll
            for (int r = 0; r < 4; r++) {
                const int row = m0 + i * 16 + r0 + r;
                Df[(size_t)row * N + col] =
                    acc[i][j][r] + bias[col] + X[(size_t)row * N + col];
            }
        }
    }
}

extern "C" void kernel_launch(void* const* d_in, const int* in_sizes, int n_in,
                              void* d_out, int out_size, void* d_ws, size_t ws_size,
                              hipStream_t stream)
{
    const float* x   = (const float*)d_in[0];
    const float* d_w = (const float*)d_in[1];
    const float* d_g = (const float*)d_in[2];
    const float* d_b = (const float*)d_in[3];
    const float* p_w = (const float*)d_in[4];
    const float* p_g = (const float*)d_in[5];
    const float* p_b = (const float*)d_in[6];
    const float* w1w = (const float*)d_in[7];
    const float* w1b = (const float*)d_in[8];
    const float* w2w = (const float*)d_in[9];
    const float* w2b = (const float*)d_in[10];
    float* out = (float*)d_out;

    char* ws = (char*)d_ws;
    const size_t SZ = (size_t)16777216;           // 16 MB
    u16*   h    = (u16*)(ws);                     // [C][B*T] bf16
    u16*   y1gT = (u16*)(ws + SZ);                // [B*T][C] bf16
    u16*   pwT  = (u16*)(ws + 2 * SZ);            // [B][O][C] bf16
    u16*   y2T  = (u16*)(ws + 3 * SZ);            // [B*T][O] bf16
    u16*   xb   = (u16*)(ws + 4 * SZ);            // [B*T][DI] bf16 (4 MB)
    u16*   w1b16= (u16*)(ws + 4 * SZ + 4194304);  // [C][DI] bf16
    u16*   w2b16= (u16*)(ws + 4 * SZ + 4718592);  // [DI][O] bf16
    float* dwf  = (float*)(ws + 4 * SZ + 5242880);           // B*C*KW f32
    float* part = (float*)(ws + 4 * SZ + 5242880 + 294912);  // B*16*O f32

    prep_k<<<dim3(PB_PT), 256, 0, stream>>>(
        x, xb, w1w, w1b16, w2w, w2b16, d_w, d_g, dwf, p_w, p_g, part, pwT);

    // GEMM1: h[c][bt] = mish(w1[c,:] . xb[bt,:] + w1b[c]);  M=C, N=B*T, K=DI
    gemm1_k<<<dim3(BT_ / 256, C_ / 128), 512, 0, stream>>>(
        w1b16, xb, h, w1b, C_, BT_, DI_);

    dwconv_k<<<dim3(T_ / 64, C_ / 64, B_), 256, 0, stream>>>(h, dwf, d_b, y1gT);

    // GEMM2: y2T[bt][o] = (y1gT[bt,:] . pwT[b][o,:])*inv[b][o] + p_b[b][o]
    gemm2_k<<<dim3(O_ / 256, BT_ / 128), 512, 0, stream>>>(
        y1gT, pwT, y2T, p_b, part, BT_, O_, C_);

    // GEMM3: out[bt][i] = y2T[bt,:] . w2[i,:] + w2b[i] + x[bt][i];  N=DI
    gemm3_k<<<dim3(DI_ / 64, BT_ / 64), 128, 0, stream>>>(
        y2T, w2b16, out, w2b, x, BT_, DI_, O_);
}